// Round 1
// baseline (4848.676 us; speedup 1.0000x reference)
//
#include <hip/hip_runtime.h>

typedef float v2f __attribute__((ext_vector_type(2)));
typedef float v4f __attribute__((ext_vector_type(4)));

#define D_IN 14
#define HID  32

__device__ __forceinline__ float rcpf(float x) { return __builtin_amdgcn_rcpf(x); }

// 4 independent LSTMs, one wave (64 lanes) each, in a single 256-thread block.
// Lane l owns gate rows l and l+64 of the 128-row gate block:
//   lanes 0..31 : i[j] (row j)    and g[j] (row 64+j)
//   lanes 32..63: f[j] (row 32+j) and o[j] (row 96+j)
// h is broadcast via 128B of LDS per wave; c is replicated across the lane pair.
__global__ __launch_bounds__(256, 1)
void lstm4_scan(const float* __restrict__ x,
                const float* __restrict__ W_ih,
                const float* __restrict__ W_hh,
                const float* __restrict__ b_ih,
                const float* __restrict__ b_hh,
                const float* __restrict__ Wt,
                const float* __restrict__ bt,
                const float* __restrict__ Wf1,
                const float* __restrict__ bf1,
                const float* __restrict__ Wf2,
                const float* __restrict__ bf2,
                float* __restrict__ out,
                int T)
{
    __shared__ __align__(16) float hbuf[4][HID];

    const int tid  = threadIdx.x;
    const int m    = tid >> 6;        // wave id == LSTM id
    const int lane = tid & 63;
    const int hi   = lane >> 5;       // 0: (i,g) lane, 1: (f,o) lane
    const int j    = lane & 31;       // hidden index
    const int rA   = lane;            // gate row A (i or f)
    const int rB   = lane + 64;       // gate row B (g or o)

    // ---- weights into registers (persistent) ----
    v2f wah[16], wbh[16];             // W_hh rows rA, rB (32 floats each)
    {
        const v2f* pA = (const v2f*)(W_hh + (size_t)(m * 128 + rA) * HID);
        const v2f* pB = (const v2f*)(W_hh + (size_t)(m * 128 + rB) * HID);
        #pragma unroll
        for (int q = 0; q < 16; ++q) { wah[q] = pA[q]; wbh[q] = pB[q]; }
    }
    v2f wax[7], wbx[7];               // W_ih rows rA, rB (14 floats each)
    {
        const v2f* pA = (const v2f*)(W_ih + (size_t)(m * 128 + rA) * D_IN);
        const v2f* pB = (const v2f*)(W_ih + (size_t)(m * 128 + rB) * D_IN);
        #pragma unroll
        for (int q = 0; q < 7; ++q) { wax[q] = pA[q]; wbx[q] = pB[q]; }
    }
    const float bA = b_ih[m * 128 + rA] + b_hh[m * 128 + rA];
    const float bB = b_ih[m * 128 + rB] + b_hh[m * 128 + rB];

    // x stream for this LSTM: 14 floats (= 7 v2f) per step, 8B-aligned per step
    const v2f* xs = (const v2f*)(x + (size_t)m * T * D_IN);

    // ---- init state ----
    hbuf[m][j] = 0.0f;                // both pair lanes write same 0 (benign)
    float c = 0.0f;
    asm volatile("s_waitcnt lgkmcnt(0)" ::: "memory");

    // prefetch x for t=0 and t=1 (ring of 2)
    v2f xb0[7], xb1[7];
    #pragma unroll
    for (int q = 0; q < 7; ++q) { xb0[q] = xs[q]; xb1[q] = xs[7 + q]; }

#define STEP(t, xb)                                                            \
    {                                                                          \
        /* x-part of gates (independent of h -> hides LDS latency) */          \
        v2f av = {bA, 0.0f}, bv = {bB, 0.0f};                                  \
        _Pragma("unroll")                                                      \
        for (int q = 0; q < 7; ++q) {                                          \
            av = __builtin_elementwise_fma(wax[q], xb[q], av);                 \
            bv = __builtin_elementwise_fma(wbx[q], xb[q], bv);                 \
        }                                                                      \
        /* prefetch x for t+2 into the ring slot just consumed */              \
        if ((t) + 2 < T) {                                                     \
            const v2f* p = xs + (size_t)((t) + 2) * 7;                         \
            _Pragma("unroll")                                                  \
            for (int q = 0; q < 7; ++q) xb[q] = p[q];                          \
        }                                                                      \
        /* broadcast-read h from LDS (8x ds_read_b128, conflict-free) */       \
        v2f hv[16];                                                            \
        {                                                                      \
            const v4f* hp = (const v4f*)hbuf[m];                               \
            _Pragma("unroll")                                                  \
            for (int q = 0; q < 8; ++q) {                                      \
                v4f t4 = hp[q];                                                \
                v2f hlo = {t4.x, t4.y};                                        \
                v2f hhi = {t4.z, t4.w};                                        \
                hv[2 * q]     = hlo;                                           \
                hv[2 * q + 1] = hhi;                                           \
            }                                                                  \
        }                                                                      \
        /* 2 gate dot-products, packed f32 FMA, 4 independent chains */        \
        v2f a0 = av, a1 = {0.0f, 0.0f}, b0 = bv, b1 = {0.0f, 0.0f};            \
        _Pragma("unroll")                                                      \
        for (int q = 0; q < 16; q += 2) {                                      \
            a0 = __builtin_elementwise_fma(wah[q],     hv[q],     a0);         \
            a1 = __builtin_elementwise_fma(wah[q + 1], hv[q + 1], a1);         \
            b0 = __builtin_elementwise_fma(wbh[q],     hv[q],     b0);         \
            b1 = __builtin_elementwise_fma(wbh[q + 1], hv[q + 1], b1);         \
        }                                                                      \
        float accA = (a0.x + a0.y) + (a1.x + a1.y);                            \
        float accB = (b0.x + b0.y) + (b1.x + b1.y);                            \
        /* activations: actA = sigmoid(i|f); actB = tanh(g) | sigmoid(o) */    \
        float actA = rcpf(1.0f + __expf(-accA));                               \
        float eB   = __expf(hi ? -accB : 2.0f * accB);                         \
        float rB_  = rcpf(1.0f + eB);                                          \
        float actB = hi ? rB_ : 1.0f - 2.0f * rB_;                             \
        /* pair exchange: hi=0 sends u = sig(i)*tanh(g); hi=1 sends sig(f) */  \
        float x0 = hi ? actA : actA * actB;                                    \
        float y0 = __shfl_xor(x0, 32);                                         \
        float y1 = __shfl_xor(actB, 32);                                       \
        float u  = hi ? y0 : x0;                                               \
        float sf = hi ? actA : y0;                                             \
        float so = hi ? actB : y1;                                             \
        /* replicated state update in both pair lanes (identical fp ops) */    \
        c = __builtin_fmaf(sf, c, u);                                          \
        float tc = 1.0f - 2.0f * rcpf(1.0f + __expf(2.0f * c));                \
        hbuf[m][j] = so * tc;                                                  \
        asm volatile("s_waitcnt lgkmcnt(0)" ::: "memory");                     \
    }

    for (int t = 0; t < T; t += 2) {
        STEP(t, xb0)
        STEP(t + 1, xb1)
    }
#undef STEP

    __syncthreads();   // join the 4 independent waves; hbuf now = final h[4][32]

    // ---- heads (reference return order: target, f1, f2, f3; f3 reuses Wf2/bf2) ----
    if (tid == 0) {
        float s = bt[0];
        const float* hf = &hbuf[0][0];
        #pragma unroll
        for (int k = 0; k < 128; ++k) s += hf[k] * Wt[k];
        out[0] = s;
    } else if (tid == 1) {
        float s = bf1[0];
        #pragma unroll
        for (int k = 0; k < 32; ++k) s += hbuf[1][k] * Wf1[k];
        out[1] = s;
    } else if (tid == 2) {
        float s = bf2[0];
        #pragma unroll
        for (int k = 0; k < 32; ++k) s += hbuf[2][k] * Wf2[k];
        out[2] = s;
    } else if (tid == 3) {
        float s = bf2[0];
        #pragma unroll
        for (int k = 0; k < 32; ++k) s += hbuf[3][k] * Wf2[k];
        out[3] = s;
    }
}

extern "C" void kernel_launch(void* const* d_in, const int* in_sizes, int n_in,
                              void* d_out, int out_size, void* d_ws, size_t ws_size,
                              hipStream_t stream) {
    const float* x    = (const float*)d_in[0];
    const float* W_ih = (const float*)d_in[1];
    const float* W_hh = (const float*)d_in[2];
    const float* b_ih = (const float*)d_in[3];
    const float* b_hh = (const float*)d_in[4];
    const float* Wt   = (const float*)d_in[5];
    const float* bt   = (const float*)d_in[6];
    const float* Wf1  = (const float*)d_in[7];
    const float* bf1  = (const float*)d_in[8];
    const float* Wf2  = (const float*)d_in[9];
    const float* bf2  = (const float*)d_in[10];

    const int T = in_sizes[0] / (4 * D_IN);   // 16384

    lstm4_scan<<<1, 256, 0, stream>>>(x, W_ih, W_hh, b_ih, b_hh,
                                      Wt, bt, Wf1, bf1, Wf2, bf2,
                                      (float*)d_out, T);
}